// Round 4
// baseline (1013.945 us; speedup 1.0000x reference)
//
#include <hip/hip_runtime.h>

// Round 4: swapped-operand fp8 weight-resident persistent RNN.
// Compute h_new^T = Wh^T (A, regs) · h^T (B, LDS) so D cols = batch rows:
// each thread owns ONE batch row and 4x4-consecutive output cols ->
// epilogue = 4 packed ds_write_b32, 1 mask read, 8 cvt_pk (was 16 b8 writes,
// 4 mask reads, 16 cvts). t-loop unrolled x2 -> ping/pong LDS offsets are
// compile-time -> all LDS addresses loop-invariant (hoisted).

typedef __attribute__((ext_vector_type(4))) float f32x4_t;

constexpr int Bn = 256, Tn = 512, En = 100, Un = 512;
constexpr int D1n = 1024, D2n = 1024, Cn = 10;
constexpr float QS  = 256.f;               // quant scale 2^8
constexpr float INV = 1.52587890625e-05f;  // 2^-16

// ---- fp8 e4m3fn conversion helpers ----------------------------------------
__device__ __forceinline__ unsigned f2e4m3_sw(float x) {
    unsigned u = __float_as_uint(x);
    unsigned sgn = (u >> 24) & 0x80;
    float a = __uint_as_float(u & 0x7FFFFFFF);
    if (a >= 448.f) return sgn | 0x7E;
    if (a < 0.015625f) {
        unsigned q = (unsigned)__float2int_rn(a * 512.f);
        return sgn | q;
    }
    int e = (int)((u >> 23) & 0xFF) - 127;
    unsigned m = u & 0x7FFFFF;
    unsigned mant = m >> 20, rem = m & 0xFFFFF;
    if (rem > 0x80000 || (rem == 0x80000 && (mant & 1))) {
        if (++mant == 8) { mant = 0; ++e; }
    }
    if (e > 8) return sgn | 0x7E;
    return sgn | ((unsigned)(e + 7) << 3) | mant;
}

__device__ __forceinline__ unsigned cvt1(float x) {
#if __has_builtin(__builtin_amdgcn_cvt_pk_fp8_f32)
    return (unsigned)__builtin_amdgcn_cvt_pk_fp8_f32(x, x, 0, false) & 0xFFu;
#else
    return f2e4m3_sw(x);
#endif
}

__device__ __forceinline__ unsigned pk4(float a, float b, float c, float d) {
#if __has_builtin(__builtin_amdgcn_cvt_pk_fp8_f32)
    int r = __builtin_amdgcn_cvt_pk_fp8_f32(a, b, 0, false);
    r = __builtin_amdgcn_cvt_pk_fp8_f32(c, d, r, true);
    return (unsigned)r;
#else
    return f2e4m3_sw(a) | (f2e4m3_sw(b) << 8) | (f2e4m3_sw(c) << 16) |
           (f2e4m3_sw(d) << 24);
#endif
}

// ---------------------------------------------------------------------------
// Pack Wh [512][512] f32 -> fp8 fragment order (scaled by QS).
// frag (nt,kt): lane l, byte j holds Wh[kt*32+(l>>4)*8+j][nt*16+(l&15)].
// (Serves as A-fragment of Wh^T: A[row=n][k] with n = nt*16+(l&15).)
// ---------------------------------------------------------------------------
__global__ __launch_bounds__(256) void pack_wh8(const float* __restrict__ Wh,
                                                unsigned char* __restrict__ P) {
    int e = blockIdx.x * 256 + threadIdx.x;          // < 262144
    int j = e & 7, l = (e >> 3) & 63, kt = (e >> 9) & 15, nt = e >> 13;
    int k = kt * 32 + (l >> 4) * 8 + j;
    int c = nt * 16 + (l & 15);
    P[e] = (unsigned char)cvt1(Wh[k * Un + c] * QS);
}

__global__ __launch_bounds__(256) void pack_wx8(const float* __restrict__ Wx,
                                                unsigned char* __restrict__ P) {
    int e = blockIdx.x * 256 + threadIdx.x;          // < 65536
    int j = e & 7, l = (e >> 3) & 63, kt = (e >> 9) & 3, nt = e >> 11;
    int k = kt * 32 + (l >> 4) * 8 + j;
    int c = nt * 16 + (l & 15);
    P[e] = (k < En) ? (unsigned char)cvt1(Wx[k * Un + c] * QS) : 0;
}

// ---------------------------------------------------------------------------
// Persistent RNN. LDS: H0@0(8192) H1@8192 X0@16384(2048) X1@18432
//                      TOK@20480(16384, row<<2 swizzled) -> 36 KB.
// H layout: [b=16][k=512] fp8, byte ^ (b<<3). X: [b=16][k=128] fp8, same swz.
// ---------------------------------------------------------------------------
__global__ __launch_bounds__(512, 2) void rnn_persist8(
    const int* __restrict__ tokens, const float* __restrict__ emb,
    const float* __restrict__ b_rnn,
    const long* __restrict__ WhP8, const long* __restrict__ WxP8,
    float* __restrict__ h_final)
{
    __shared__ char sh[36864];
    char* H0 = sh;            char* H1 = sh + 8192;
    char* X0 = sh + 16384;    char* X1 = sh + 18432;
    char* TOKB = sh + 20480;

    const int tid  = threadIdx.x;
    const int lane = tid & 63;
    const int wv   = tid >> 6;
    const int r0   = blockIdx.x * 16;

    const int r16  = lane & 15;         // batch row owned by this thread (D col)
    const int q    = lane >> 4;         // 0..3
    const int aswz = r16 << 3;

    // tokens -> LDS ushort, swizzled so per-step mask reads are conflict-free
    for (int f = tid; f < 16 * Tn; f += 512) {
        int row = f >> 9, tt = f & 511;
        *(ushort*)(TOKB + ((((row << 10) | (tt << 1))) ^ (row << 2))) =
            (ushort)tokens[r0 * Tn + f];
    }
    {   // zero H0 and X0+X1
        int* z = (int*)sh;
        for (int f = tid; f < 2048; f += 512) z[f] = 0;
        int* zx = (int*)(sh + 16384);
        for (int f = tid; f < 1024; f += 512) zx[f] = 0;
    }
    __syncthreads();

    // ---- weight fragments -> registers (A operand = Wh^T / Wx^T) ----
    long whf[16][4], wxf[4][4];
#pragma unroll
    for (int kt = 0; kt < 16; ++kt)
#pragma unroll
        for (int p = 0; p < 4; ++p)
            whf[kt][p] = WhP8[((wv * 4 + p) * 16 + kt) * 64 + lane];
#pragma unroll
    for (int kt = 0; kt < 4; ++kt)
#pragma unroll
        for (int p = 0; p < 4; ++p)
            wxf[kt][p] = WxP8[((wv * 4 + p) * 4 + kt) * 64 + lane];

    // bias for the 16 owned output cols: n = (wv*4+p)*16 + q*4 + j
    float bias_r[4][4];
#pragma unroll
    for (int p = 0; p < 4; ++p)
#pragma unroll
        for (int j = 0; j < 4; ++j)
            bias_r[p][j] = b_rnn[(wv * 4 + p) * 16 + q * 4 + j];

    // embedding prefetch mapping: 400 threads = 16 rows x 25 float4
    const int prow = tid / 25;
    const int pc4  = tid - prow * 25;
    const bool is_pref = (tid < 400);
    const int pxaddr = (prow * 128 + pc4 * 4) ^ (prow << 3);

    if (is_pref) {   // x for t=0
        int tk = (int)*(const ushort*)(TOKB + (((prow << 10)) ^ (prow << 2)));
        float4 v = *(const float4*)(emb + tk * En + pc4 * 4);
        *(unsigned*)(X0 + pxaddr) = pk4(v.x * QS, v.y * QS, v.z * QS, v.w * QS);
    }
    __syncthreads();

    float hprev[4][4];
#pragma unroll
    for (int p = 0; p < 4; ++p)
#pragma unroll
        for (int j = 0; j < 4; ++j) hprev[p][j] = 0.f;

#define RNN_STEP(T, HC, HN, XC, XN)                                            \
    {                                                                          \
        const int t = (T);                                                     \
        float4 pref;                                                           \
        const bool dp = is_pref && (t + 1 < Tn);                               \
        if (dp) {                                                              \
            int tk = (int)*(const ushort*)(TOKB +                              \
                ((((prow << 10) | ((t + 1) << 1))) ^ (prow << 2)));            \
            pref = *(const float4*)(emb + tk * En + pc4 * 4);                  \
        }                                                                      \
        f32x4_t acc[4];                                                        \
        _Pragma("unroll")                                                      \
        for (int p = 0; p < 4; ++p) acc[p] = (f32x4_t){0.f, 0.f, 0.f, 0.f};    \
        _Pragma("unroll")                                                      \
        for (int kt = 0; kt < 16; ++kt) {                                      \
            long a = *(const long*)((HC) +                                     \
                ((r16 * 512 + kt * 32 + q * 8) ^ aswz));                       \
            _Pragma("unroll")                                                  \
            for (int p = 0; p < 4; ++p)                                        \
                acc[p] = __builtin_amdgcn_mfma_f32_16x16x32_fp8_fp8(           \
                    whf[kt][p], a, acc[p], 0, 0, 0);                           \
        }                                                                      \
        _Pragma("unroll")                                                      \
        for (int kt = 0; kt < 4; ++kt) {                                       \
            long a = *(const long*)((XC) +                                     \
                ((r16 * 128 + kt * 32 + q * 8) ^ aswz));                       \
            _Pragma("unroll")                                                  \
            for (int p = 0; p < 4; ++p)                                        \
                acc[p] = __builtin_amdgcn_mfma_f32_16x16x32_fp8_fp8(           \
                    wxf[kt][p], a, acc[p], 0, 0, 0);                           \
        }                                                                      \
        const bool mk = *(const ushort*)(TOKB +                                \
            ((((r16 << 10) | (t << 1))) ^ (r16 << 2))) != 0;                   \
        _Pragma("unroll")                                                      \
        for (int p = 0; p < 4; ++p) {                                          \
            float v0 = fmaxf(acc[p][0] * INV + bias_r[p][0], 0.f);             \
            float v1 = fmaxf(acc[p][1] * INV + bias_r[p][1], 0.f);             \
            float v2 = fmaxf(acc[p][2] * INV + bias_r[p][2], 0.f);             \
            float v3 = fmaxf(acc[p][3] * INV + bias_r[p][3], 0.f);             \
            v0 = mk ? v0 : hprev[p][0];  v1 = mk ? v1 : hprev[p][1];           \
            v2 = mk ? v2 : hprev[p][2];  v3 = mk ? v3 : hprev[p][3];           \
            hprev[p][0] = v0; hprev[p][1] = v1;                                \
            hprev[p][2] = v2; hprev[p][3] = v3;                                \
            *(unsigned*)((HN) +                                                \
                ((r16 * 512 + (wv * 4 + p) * 16 + q * 4) ^ aswz)) =            \
                pk4(v0 * QS, v1 * QS, v2 * QS, v3 * QS);                       \
        }                                                                      \
        if (dp) {                                                              \
            *(unsigned*)((XN) + pxaddr) =                                      \
                pk4(pref.x * QS, pref.y * QS, pref.z * QS, pref.w * QS);       \
        }                                                                      \
        __syncthreads();                                                       \
    }

    for (int t2 = 0; t2 < Tn; t2 += 2) {
        RNN_STEP(t2,     H0, H1, X0, X1)
        RNN_STEP(t2 + 1, H1, H0, X1, X0)
    }
#undef RNN_STEP

    // final h from exact fp32 registers: row = r16, cols n
#pragma unroll
    for (int p = 0; p < 4; ++p) {
        int n = (wv * 4 + p) * 16 + q * 4;
#pragma unroll
        for (int j = 0; j < 4; ++j)
            h_final[(r0 + r16) * Un + n + j] = hprev[p][j];
    }
}

// ---------------------------------------------------------------------------
// MLP head (unchanged)
// ---------------------------------------------------------------------------
template <int K, bool RELU>
__global__ __launch_bounds__(256) void fc(
    const float* __restrict__ in, const float* __restrict__ W,
    const float* __restrict__ b, float* __restrict__ out, int N)
{
    __shared__ float in_lds[16][K];
    const int tid = threadIdx.x;
    const int r0  = blockIdx.y * 16;
    const int c0  = blockIdx.x * 32;

    for (int i = tid; i < 16 * K; i += 256) {
        int r = i / K, c = i - r * K;
        in_lds[r][c] = in[(r0 + r) * K + c];
    }
    __syncthreads();

    const int col = c0 + (tid & 31);
    const int rb  = (tid >> 5) * 2;

    float acc0 = b[col];
    float acc1 = acc0;
    const float4* i0v = (const float4*)(&in_lds[rb][0]);
    const float4* i1v = (const float4*)(&in_lds[rb + 1][0]);
    for (int k4 = 0; k4 < K / 4; ++k4) {
        float4 a = i0v[k4];
        float4 c = i1v[k4];
        int k = k4 * 4;
        float w0 = W[(k + 0) * N + col];
        float w1 = W[(k + 1) * N + col];
        float w2 = W[(k + 2) * N + col];
        float w3 = W[(k + 3) * N + col];
        acc0 += a.x * w0; acc0 += a.y * w1; acc0 += a.z * w2; acc0 += a.w * w3;
        acc1 += c.x * w0; acc1 += c.y * w1; acc1 += c.z * w2; acc1 += c.w * w3;
    }
    if (RELU) { acc0 = fmaxf(acc0, 0.f); acc1 = fmaxf(acc1, 0.f); }
    out[(r0 + rb) * N + col]     = acc0;
    out[(r0 + rb + 1) * N + col] = acc1;
}

__global__ __launch_bounds__(64) void head_softmax(
    const float* __restrict__ h2, const float* __restrict__ Wo,
    const float* __restrict__ bo, float* __restrict__ out)
{
    const int b    = blockIdx.x;
    const int lane = threadIdx.x;

    float acc[Cn];
#pragma unroll
    for (int c = 0; c < Cn; ++c) acc[c] = 0.f;

    for (int k = lane; k < D2n; k += 64) {
        float hv = h2[b * D2n + k];
#pragma unroll
        for (int c = 0; c < Cn; ++c) acc[c] += hv * Wo[k * Cn + c];
    }
#pragma unroll
    for (int c = 0; c < Cn; ++c) {
#pragma unroll
        for (int off = 32; off > 0; off >>= 1)
            acc[c] += __shfl_down(acc[c], off);
    }
    if (lane == 0) {
        float l[Cn], mx = -1e30f;
#pragma unroll
        for (int c = 0; c < Cn; ++c) { l[c] = acc[c] + bo[c]; mx = fmaxf(mx, l[c]); }
        float s = 0.f;
#pragma unroll
        for (int c = 0; c < Cn; ++c) { l[c] = __expf(l[c] - mx); s += l[c]; }
        float inv = 1.f / s;
#pragma unroll
        for (int c = 0; c < Cn; ++c) out[b * Cn + c] = l[c] * inv;
    }
}

extern "C" void kernel_launch(void* const* d_in, const int* in_sizes, int n_in,
                              void* d_out, int out_size, void* d_ws, size_t ws_size,
                              hipStream_t stream)
{
    const int*   tokens = (const int*)d_in[0];
    const float* emb    = (const float*)d_in[1];
    const float* Wx     = (const float*)d_in[2];
    const float* Wh     = (const float*)d_in[3];
    const float* b_rnn  = (const float*)d_in[4];
    const float* W1     = (const float*)d_in[5];
    const float* b1     = (const float*)d_in[6];
    const float* W2     = (const float*)d_in[7];
    const float* b2     = (const float*)d_in[8];
    const float* Wo     = (const float*)d_in[9];
    const float* bo     = (const float*)d_in[10];
    float* out = (float*)d_out;

    char* ws = (char*)d_ws;
    unsigned char* WhP8 = (unsigned char*)ws;                 // 256 KB
    unsigned char* WxP8 = (unsigned char*)(ws + (256 << 10)); // 64 KB
    float* h_last = (float*)(ws + (320 << 10));               // 512 KB
    float* h1     = (float*)(ws + (832 << 10));               // 1 MB
    float* h2     = (float*)(ws + (1856 << 10));              // 1 MB

    pack_wh8<<<1024, 256, 0, stream>>>(Wh, WhP8);
    pack_wx8<<<256, 256, 0, stream>>>(Wx, WxP8);

    rnn_persist8<<<Bn / 16, 512, 0, stream>>>(
        tokens, emb, b_rnn, (const long*)WhP8, (const long*)WxP8, h_last);

    dim3 bs(256);
    fc<Un, true><<<dim3(D1n / 32, Bn / 16), bs, 0, stream>>>(h_last, W1, b1, h1, D1n);
    fc<D1n, true><<<dim3(D2n / 32, Bn / 16), bs, 0, stream>>>(h1, W2, b2, h2, D2n);
    head_softmax<<<Bn, 64, 0, stream>>>(h2, Wo, bo, out);
}

// Round 5
// 586.674 us; speedup vs baseline: 1.7283x; 1.7283x over previous
//
#include <hip/hip_runtime.h>

// Round 5: MX-scaled fp8 (K=128) weight-resident persistent RNN.
// mfma_scale_f32_16x16x128_f8f6f4 with unit scales (0x7F) = plain fp8 GEMM
// at 2.28x the non-scaled fp8 rate. Weights stay register-resident
// (v8i32 fragments, 32 B/lane/fragment). LDS swizzle ^(r16<<4) keeps the
// 16B B-operand reads contiguous and bank-uniform. Epilogue/D-layout
// unchanged (shape-determined).

typedef __attribute__((ext_vector_type(8))) int i32x8_t;
typedef __attribute__((ext_vector_type(4))) float f32x4_t;

constexpr int Bn = 256, Tn = 512, En = 100, Un = 512;
constexpr int D1n = 1024, D2n = 1024, Cn = 10;
constexpr float QS  = 256.f;               // quant scale 2^8
constexpr float INV = 1.52587890625e-05f;  // 2^-16
constexpr int USC = 0x7F7F7F7F;            // unit E8M0 scales (2^0)

// ---- fp8 e4m3fn conversion helpers ----------------------------------------
__device__ __forceinline__ unsigned f2e4m3_sw(float x) {
    unsigned u = __float_as_uint(x);
    unsigned sgn = (u >> 24) & 0x80;
    float a = __uint_as_float(u & 0x7FFFFFFF);
    if (a >= 448.f) return sgn | 0x7E;
    if (a < 0.015625f) {
        unsigned q = (unsigned)__float2int_rn(a * 512.f);
        return sgn | q;
    }
    int e = (int)((u >> 23) & 0xFF) - 127;
    unsigned m = u & 0x7FFFFF;
    unsigned mant = m >> 20, rem = m & 0xFFFFF;
    if (rem > 0x80000 || (rem == 0x80000 && (mant & 1))) {
        if (++mant == 8) { mant = 0; ++e; }
    }
    if (e > 8) return sgn | 0x7E;
    return sgn | ((unsigned)(e + 7) << 3) | mant;
}

__device__ __forceinline__ unsigned cvt1(float x) {
#if __has_builtin(__builtin_amdgcn_cvt_pk_fp8_f32)
    return (unsigned)__builtin_amdgcn_cvt_pk_fp8_f32(x, x, 0, false) & 0xFFu;
#else
    return f2e4m3_sw(x);
#endif
}

__device__ __forceinline__ unsigned pk4(float a, float b, float c, float d) {
#if __has_builtin(__builtin_amdgcn_cvt_pk_fp8_f32)
    int r = __builtin_amdgcn_cvt_pk_fp8_f32(a, b, 0, false);
    r = __builtin_amdgcn_cvt_pk_fp8_f32(c, d, r, true);
    return (unsigned)r;
#else
    return f2e4m3_sw(a) | (f2e4m3_sw(b) << 8) | (f2e4m3_sw(c) << 16) |
           (f2e4m3_sw(d) << 24);
#endif
}

// ---------------------------------------------------------------------------
// Pack Wh [512][512] f32 -> fp8 MX A-fragment order (scaled by QS).
// frag (nt,kc): lane l, byte j holds Wh^T A-elem: row n = nt*16+(l&15),
// k = kc*128 + (l>>4)*32 + j.  e = ((nt*4+kc)*64 + l)*32 + j.
// ---------------------------------------------------------------------------
__global__ __launch_bounds__(256) void pack_wh8(const float* __restrict__ Wh,
                                                unsigned char* __restrict__ P) {
    int e = blockIdx.x * 256 + threadIdx.x;          // < 262144
    int j = e & 31, l = (e >> 5) & 63, kc = (e >> 11) & 3, nt = e >> 13;
    int k = kc * 128 + (l >> 4) * 32 + j;
    int c = nt * 16 + (l & 15);
    P[e] = (unsigned char)cvt1(Wh[k * Un + c] * QS);
}

// Wx [100][512] -> one K=128 MX fragment per n-tile (k>=100 zero-padded).
__global__ __launch_bounds__(256) void pack_wx8(const float* __restrict__ Wx,
                                                unsigned char* __restrict__ P) {
    int e = blockIdx.x * 256 + threadIdx.x;          // < 65536
    int j = e & 31, l = (e >> 5) & 63, nt = e >> 11;
    int k = (l >> 4) * 32 + j;
    int c = nt * 16 + (l & 15);
    P[e] = (k < En) ? (unsigned char)cvt1(Wx[k * Un + c] * QS) : 0;
}

// ---------------------------------------------------------------------------
// Persistent RNN. LDS: H0@0(8192) H1@8192 X0@16384(2048) X1@18432
//                      TOK@20480(16384, ^(row<<2)) -> 36 KB.
// H: [b=16][k=512] fp8, byte ^ (b<<4). X: [b=16][k=128] fp8, same transform
// (bijective; write+read share it). B-frag: lane l reads 32 B at
// [col=l&15][k=(l>>4)*32 (+kc*128)].
// ---------------------------------------------------------------------------
__global__ __launch_bounds__(512, 2) void rnn_persist8(
    const int* __restrict__ tokens, const float* __restrict__ emb,
    const float* __restrict__ b_rnn,
    const unsigned char* __restrict__ WhP8, const unsigned char* __restrict__ WxP8,
    float* __restrict__ h_final)
{
    __shared__ char sh[36864];
    char* H0 = sh;            char* H1 = sh + 8192;
    char* X0 = sh + 16384;    char* X1 = sh + 18432;
    char* TOKB = sh + 20480;

    const int tid  = threadIdx.x;
    const int lane = tid & 63;
    const int wv   = tid >> 6;
    const int r0   = blockIdx.x * 16;

    const int r16  = lane & 15;         // batch row owned (B col / D col)
    const int q    = lane >> 4;         // 0..3 (k-block group / D row group)
    const int bswz = r16 << 4;

    for (int f = tid; f < 16 * Tn; f += 512) {
        int row = f >> 9, tt = f & 511;
        *(ushort*)(TOKB + ((((row << 10) | (tt << 1))) ^ (row << 2))) =
            (ushort)tokens[r0 * Tn + f];
    }
    {   // zero H0 and X0+X1
        int* z = (int*)sh;
        for (int f = tid; f < 2048; f += 512) z[f] = 0;
        int* zx = (int*)(sh + 16384);
        for (int f = tid; f < 1024; f += 512) zx[f] = 0;
    }
    __syncthreads();

    // ---- weight fragments -> registers (A operand = Wh^T / Wx^T) ----
    i32x8_t whf[4][4], wxf[4];
#pragma unroll
    for (int kc = 0; kc < 4; ++kc)
#pragma unroll
        for (int p = 0; p < 4; ++p)
            whf[kc][p] = *(const i32x8_t*)(WhP8 +
                (((wv * 4 + p) * 4 + kc) * 64 + lane) * 32);
#pragma unroll
    for (int p = 0; p < 4; ++p)
        wxf[p] = *(const i32x8_t*)(WxP8 + ((wv * 4 + p) * 64 + lane) * 32);

    // bias for owned output cols: n = (wv*4+p)*16 + q*4 + j
    float bias_r[4][4];
#pragma unroll
    for (int p = 0; p < 4; ++p)
#pragma unroll
        for (int j = 0; j < 4; ++j)
            bias_r[p][j] = b_rnn[(wv * 4 + p) * 16 + q * 4 + j];

    // embedding prefetch mapping: 400 threads = 16 rows x 25 float4
    const int prow = tid / 25;
    const int pc4  = tid - prow * 25;
    const bool is_pref = (tid < 400);
    const int pxaddr = (prow * 128 + pc4 * 4) ^ (prow << 4);

    if (is_pref) {   // x for t=0
        int tk = (int)*(const ushort*)(TOKB + (((prow << 10)) ^ (prow << 2)));
        float4 v = *(const float4*)(emb + tk * En + pc4 * 4);
        *(unsigned*)(X0 + pxaddr) = pk4(v.x * QS, v.y * QS, v.z * QS, v.w * QS);
    }
    __syncthreads();

    float hprev[4][4];
#pragma unroll
    for (int p = 0; p < 4; ++p)
#pragma unroll
        for (int j = 0; j < 4; ++j) hprev[p][j] = 0.f;

#define RNN_STEP(T, HC, HN, XC, XN)                                            \
    {                                                                          \
        const int t = (T);                                                     \
        float4 pref;                                                           \
        const bool dp = is_pref && (t + 1 < Tn);                               \
        if (dp) {                                                              \
            int tk = (int)*(const ushort*)(TOKB +                              \
                ((((prow << 10) | ((t + 1) << 1))) ^ (prow << 2)));            \
            pref = *(const float4*)(emb + tk * En + pc4 * 4);                  \
        }                                                                      \
        f32x4_t acc[4];                                                        \
        _Pragma("unroll")                                                      \
        for (int p = 0; p < 4; ++p) acc[p] = (f32x4_t){0.f, 0.f, 0.f, 0.f};    \
        _Pragma("unroll")                                                      \
        for (int kc = 0; kc < 4; ++kc) {                                       \
            const int bb = r16 * 512 + kc * 128 + q * 32;                      \
            uint4 blo = *(const uint4*)((HC) + ((bb) ^ bswz));                 \
            uint4 bhi = *(const uint4*)((HC) + ((bb + 16) ^ bswz));            \
            i32x8_t bf = {(int)blo.x, (int)blo.y, (int)blo.z, (int)blo.w,      \
                          (int)bhi.x, (int)bhi.y, (int)bhi.z, (int)bhi.w};     \
            _Pragma("unroll")                                                  \
            for (int p = 0; p < 4; ++p)                                        \
                acc[p] = __builtin_amdgcn_mfma_scale_f32_16x16x128_f8f6f4(     \
                    whf[kc][p], bf, acc[p], 0, 0, 0, USC, 0, USC);             \
        }                                                                      \
        {                                                                      \
            const int xb = r16 * 128 + q * 32;                                 \
            uint4 blo = *(const uint4*)((XC) + ((xb) ^ bswz));                 \
            uint4 bhi = *(const uint4*)((XC) + ((xb + 16) ^ bswz));            \
            i32x8_t bf = {(int)blo.x, (int)blo.y, (int)blo.z, (int)blo.w,      \
                          (int)bhi.x, (int)bhi.y, (int)bhi.z, (int)bhi.w};     \
            _Pragma("unroll")                                                  \
            for (int p = 0; p < 4; ++p)                                        \
                acc[p] = __builtin_amdgcn_mfma_scale_f32_16x16x128_f8f6f4(     \
                    wxf[p], bf, acc[p], 0, 0, 0, USC, 0, USC);                 \
        }                                                                      \
        const bool mk = *(const ushort*)(TOKB +                                \
            ((((r16 << 10) | (t << 1))) ^ (r16 << 2))) != 0;                   \
        _Pragma("unroll")                                                      \
        for (int p = 0; p < 4; ++p) {                                          \
            float v0 = fmaxf(acc[p][0] * INV + bias_r[p][0], 0.f);             \
            float v1 = fmaxf(acc[p][1] * INV + bias_r[p][1], 0.f);             \
            float v2 = fmaxf(acc[p][2] * INV + bias_r[p][2], 0.f);             \
            float v3 = fmaxf(acc[p][3] * INV + bias_r[p][3], 0.f);             \
            v0 = mk ? v0 : hprev[p][0];  v1 = mk ? v1 : hprev[p][1];           \
            v2 = mk ? v2 : hprev[p][2];  v3 = mk ? v3 : hprev[p][3];           \
            hprev[p][0] = v0; hprev[p][1] = v1;                                \
            hprev[p][2] = v2; hprev[p][3] = v3;                                \
            *(unsigned*)((HN) +                                                \
                ((r16 * 512 + (wv * 4 + p) * 16 + q * 4) ^ bswz)) =            \
                pk4(v0 * QS, v1 * QS, v2 * QS, v3 * QS);                       \
        }                                                                      \
        if (dp) {                                                              \
            *(unsigned*)((XN) + pxaddr) =                                      \
                pk4(pref.x * QS, pref.y * QS, pref.z * QS, pref.w * QS);       \
        }                                                                      \
        __syncthreads();                                                       \
    }

    for (int t2 = 0; t2 < Tn; t2 += 2) {
        RNN_STEP(t2,     H0, H1, X0, X1)
        RNN_STEP(t2 + 1, H1, H0, X1, X0)
    }
#undef RNN_STEP

    // final h from exact fp32 registers: row = r16, cols n
#pragma unroll
    for (int p = 0; p < 4; ++p) {
        int n = (wv * 4 + p) * 16 + q * 4;
#pragma unroll
        for (int j = 0; j < 4; ++j)
            h_final[(r0 + r16) * Un + n + j] = hprev[p][j];
    }
}

// ---------------------------------------------------------------------------
// MLP head (unchanged)
// ---------------------------------------------------------------------------
template <int K, bool RELU>
__global__ __launch_bounds__(256) void fc(
    const float* __restrict__ in, const float* __restrict__ W,
    const float* __restrict__ b, float* __restrict__ out, int N)
{
    __shared__ float in_lds[16][K];
    const int tid = threadIdx.x;
    const int r0  = blockIdx.y * 16;
    const int c0  = blockIdx.x * 32;

    for (int i = tid; i < 16 * K; i += 256) {
        int r = i / K, c = i - r * K;
        in_lds[r][c] = in[(r0 + r) * K + c];
    }
    __syncthreads();

    const int col = c0 + (tid & 31);
    const int rb  = (tid >> 5) * 2;

    float acc0 = b[col];
    float acc1 = acc0;
    const float4* i0v = (const float4*)(&in_lds[rb][0]);
    const float4* i1v = (const float4*)(&in_lds[rb + 1][0]);
    for (int k4 = 0; k4 < K / 4; ++k4) {
        float4 a = i0v[k4];
        float4 c = i1v[k4];
        int k = k4 * 4;
        float w0 = W[(k + 0) * N + col];
        float w1 = W[(k + 1) * N + col];
        float w2 = W[(k + 2) * N + col];
        float w3 = W[(k + 3) * N + col];
        acc0 += a.x * w0; acc0 += a.y * w1; acc0 += a.z * w2; acc0 += a.w * w3;
        acc1 += c.x * w0; acc1 += c.y * w1; acc1 += c.z * w2; acc1 += c.w * w3;
    }
    if (RELU) { acc0 = fmaxf(acc0, 0.f); acc1 = fmaxf(acc1, 0.f); }
    out[(r0 + rb) * N + col]     = acc0;
    out[(r0 + rb + 1) * N + col] = acc1;
}

__global__ __launch_bounds__(64) void head_softmax(
    const float* __restrict__ h2, const float* __restrict__ Wo,
    const float* __restrict__ bo, float* __restrict__ out)
{
    const int b    = blockIdx.x;
    const int lane = threadIdx.x;

    float acc[Cn];
#pragma unroll
    for (int c = 0; c < Cn; ++c) acc[c] = 0.f;

    for (int k = lane; k < D2n; k += 64) {
        float hv = h2[b * D2n + k];
#pragma unroll
        for (int c = 0; c < Cn; ++c) acc[c] += hv * Wo[k * Cn + c];
    }
#pragma unroll
    for (int c = 0; c < Cn; ++c) {
#pragma unroll
        for (int off = 32; off > 0; off >>= 1)
            acc[c] += __shfl_down(acc[c], off);
    }
    if (lane == 0) {
        float l[Cn], mx = -1e30f;
#pragma unroll
        for (int c = 0; c < Cn; ++c) { l[c] = acc[c] + bo[c]; mx = fmaxf(mx, l[c]); }
        float s = 0.f;
#pragma unroll
        for (int c = 0; c < Cn; ++c) { l[c] = __expf(l[c] - mx); s += l[c]; }
        float inv = 1.f / s;
#pragma unroll
        for (int c = 0; c < Cn; ++c) out[b * Cn + c] = l[c] * inv;
    }
}

extern "C" void kernel_launch(void* const* d_in, const int* in_sizes, int n_in,
                              void* d_out, int out_size, void* d_ws, size_t ws_size,
                              hipStream_t stream)
{
    const int*   tokens = (const int*)d_in[0];
    const float* emb    = (const float*)d_in[1];
    const float* Wx     = (const float*)d_in[2];
    const float* Wh     = (const float*)d_in[3];
    const float* b_rnn  = (const float*)d_in[4];
    const float* W1     = (const float*)d_in[5];
    const float* b1     = (const float*)d_in[6];
    const float* W2     = (const float*)d_in[7];
    const float* b2     = (const float*)d_in[8];
    const float* Wo     = (const float*)d_in[9];
    const float* bo     = (const float*)d_in[10];
    float* out = (float*)d_out;

    char* ws = (char*)d_ws;
    unsigned char* WhP8 = (unsigned char*)ws;                 // 256 KB
    unsigned char* WxP8 = (unsigned char*)(ws + (256 << 10)); // 64 KB
    float* h_last = (float*)(ws + (320 << 10));               // 512 KB
    float* h1     = (float*)(ws + (832 << 10));               // 1 MB
    float* h2     = (float*)(ws + (1856 << 10));              // 1 MB

    pack_wh8<<<1024, 256, 0, stream>>>(Wh, WhP8);
    pack_wx8<<<256, 256, 0, stream>>>(Wx, WxP8);

    rnn_persist8<<<Bn / 16, 512, 0, stream>>>(
        tokens, emb, b_rnn, WhP8, WxP8, h_last);

    dim3 bs(256);
    fc<Un, true><<<dim3(D1n / 32, Bn / 16), bs, 0, stream>>>(h_last, W1, b1, h1, D1n);
    fc<D1n, true><<<dim3(D2n / 32, Bn / 16), bs, 0, stream>>>(h1, W2, b2, h2, D2n);
    head_softmax<<<Bn, 64, 0, stream>>>(h2, Wo, bo, out);
}